// Round 1
// baseline (2978.722 us; speedup 1.0000x reference)
//
#include <hip/hip_runtime.h>

typedef unsigned short u16;
typedef unsigned int u32;
typedef __bf16 bf16x8 __attribute__((ext_vector_type(8)));
typedef float f32x4 __attribute__((ext_vector_type(4)));
typedef u16 u16x8 __attribute__((ext_vector_type(8)));
typedef u16 u16x4 __attribute__((ext_vector_type(4)));

static __device__ __forceinline__ u16 f2bf(float f) {
  u32 u = __builtin_bit_cast(u32, f);
  u32 r = (u + 0x7FFFu + ((u >> 16) & 1u)) >> 16;  // RNE; inputs finite
  return (u16)r;
}

// ---------------- embedding: x = tok_emb[idx] + pos_emb ----------------
__global__ void k_embed(const int* __restrict__ idx, const float* __restrict__ tok,
                        const float* __restrict__ pos, float* __restrict__ x) {
  int row = blockIdx.x;            // b*1024 + t
  int t = row & 1023;
  int id = idx[row];
  int c = threadIdx.x * 4;
  float4 a = *(const float4*)(tok + (size_t)id * 1024 + c);
  float4 p = *(const float4*)(pos + (size_t)t * 1024 + c);
  float4 r{a.x + p.x, a.y + p.y, a.z + p.z, a.w + p.w};
  *(float4*)(x + (size_t)row * 1024 + c) = r;
}

// ---------------- layernorm (f32 in) -> bf16 out ----------------
__global__ void k_ln(const float* __restrict__ x, const float* __restrict__ sc,
                     const float* __restrict__ bi, u16* __restrict__ out) {
  int row = blockIdx.x;
  int t = threadIdx.x;
  const float* xr = x + (size_t)row * 1024;
  float4 v = *(const float4*)(xr + t * 4);
  float s = v.x + v.y + v.z + v.w;
  float ss = v.x * v.x + v.y * v.y + v.z * v.z + v.w * v.w;
  for (int d = 1; d < 64; d <<= 1) { s += __shfl_xor(s, d); ss += __shfl_xor(ss, d); }
  __shared__ float red[8];
  int wave = t >> 6, lane = t & 63;
  if (lane == 0) { red[wave] = s; red[wave + 4] = ss; }
  __syncthreads();
  s = red[0] + red[1] + red[2] + red[3];
  ss = red[4] + red[5] + red[6] + red[7];
  float mu = s * (1.0f / 1024.0f);
  float var = ss * (1.0f / 1024.0f) - mu * mu;
  float inv = rsqrtf(var + 1e-5f);
  float4 g = *(const float4*)(sc + t * 4);
  float4 b = *(const float4*)(bi + t * 4);
  u16x4 o;
  o[0] = f2bf((v.x - mu) * inv * g.x + b.x);
  o[1] = f2bf((v.y - mu) * inv * g.y + b.y);
  o[2] = f2bf((v.z - mu) * inv * g.z + b.z);
  o[3] = f2bf((v.w - mu) * inv * g.w + b.w);
  *(u16x4*)(out + (size_t)row * 1024 + t * 4) = o;
}

// ---------------- transpose+convert: f32 src[R][C] -> bf16 dst[C][R] ----------------
__launch_bounds__(1024)
__global__ void k_transpose(const float* __restrict__ src, u16* __restrict__ dst,
                            int R, int C) {
  __shared__ float tile[32][33];
  int tx = threadIdx.x, ty = threadIdx.y;
  int c = blockIdx.x * 32 + tx;
  int r = blockIdx.y * 32 + ty;
  tile[ty][tx] = src[(size_t)r * C + c];
  __syncthreads();
  int dr = blockIdx.x * 32 + ty;   // dst row = src col
  int dc = blockIdx.y * 32 + tx;   // dst col = src row
  dst[(size_t)dr * R + dc] = f2bf(tile[tx][ty]);
}

// ---------------- GEMM: C[M][N] = A[M][K](bf16) x Bt[N][K](bf16)^T ----------------
enum { EPI_QKV = 0, EPI_RES = 1, EPI_RELU = 2, EPI_OUT = 3 };

template <int EPI>
__launch_bounds__(256, 2)
__global__ void k_gemm(const u16* __restrict__ A, const u16* __restrict__ Bt,
                       const float* __restrict__ bias, float* __restrict__ fout,
                       u16* __restrict__ bout, int M, int N, int K) {
  __shared__ u16 Al[128][32];
  __shared__ u16 Bl[128][32];
  const int t = threadIdx.x;
  const int wave = t >> 6, lane = t & 63;
  const int wm = wave >> 1, wn = wave & 1;
  const int g = lane >> 4, c = lane & 15;
  const int m0 = blockIdx.x * 128, n0 = blockIdx.y * 128;

  f32x4 acc[4][4] = {};

  const int kIters = K >> 5;
  for (int kt = 0; kt < kIters; ++kt) {
    const int k0 = kt << 5;
    uint4 ra[2], rb[2];
#pragma unroll
    for (int p = 0; p < 2; ++p) {
      int chunk = t + (p << 8);
      int row = chunk >> 2, seg = chunk & 3;
      ra[p] = *(const uint4*)(A + (size_t)(m0 + row) * K + k0 + seg * 8);
      rb[p] = *(const uint4*)(Bt + (size_t)(n0 + row) * K + k0 + seg * 8);
    }
    __syncthreads();   // previous iteration's frag reads complete
#pragma unroll
    for (int p = 0; p < 2; ++p) {
      int chunk = t + (p << 8);
      int row = chunk >> 2, seg = chunk & 3;
      *(uint4*)&Al[row][seg * 8] = ra[p];
      *(uint4*)&Bl[row][seg * 8] = rb[p];
    }
    __syncthreads();
    bf16x8 af[4], bfr[4];
#pragma unroll
    for (int i = 0; i < 4; ++i) {
      af[i]  = *(const bf16x8*)&Al[wm * 64 + i * 16 + c][g * 8];
      bfr[i] = *(const bf16x8*)&Bl[wn * 64 + i * 16 + c][g * 8];
    }
#pragma unroll
    for (int i = 0; i < 4; ++i)
#pragma unroll
      for (int j = 0; j < 4; ++j)
        acc[i][j] = __builtin_amdgcn_mfma_f32_16x16x32_bf16(af[i], bfr[j], acc[i][j], 0, 0, 0);
  }

#pragma unroll
  for (int i = 0; i < 4; ++i) {
#pragma unroll
    for (int j = 0; j < 4; ++j) {
#pragma unroll
      for (int r = 0; r < 4; ++r) {
        int m = m0 + wm * 64 + i * 16 + g * 4 + r;
        int n = n0 + wn * 64 + j * 16 + c;
        float v = acc[i][j][r];
        if (EPI == EPI_QKV) {
          int which = n >> 10;
          int hh = (n >> 6) & 15, f = n & 63;
          int b = m >> 10, tt = m & 1023;
          bout[(size_t)which * 2097152 +
               ((size_t)(b * 16 + hh) * 1024 + tt) * 64 + f] = f2bf(v);
        } else if (EPI == EPI_RES) {
          size_t off = (size_t)m * N + n;
          fout[off] += v + bias[n];
        } else if (EPI == EPI_RELU) {
          float u = v + bias[n];
          bout[(size_t)m * N + n] = f2bf(u > 0.f ? u : 0.f);
        } else {
          fout[(size_t)m * N + n] = v + bias[n];
        }
      }
    }
  }
}

// ---------------- flash attention: 1 wave per (bh, 16 q-rows) ----------------
__launch_bounds__(64)
__global__ void k_attn(const u16* __restrict__ Q, const u16* __restrict__ Kb,
                       const u16* __restrict__ V, u16* __restrict__ O) {
  const int qb = blockIdx.x;       // 0..63
  const int bh = blockIdx.y;       // 0..31
  const int lane = threadIdx.x;
  const int g = lane >> 4, c = lane & 15;
  const int q0 = qb << 4;
  const u16* Qh = Q + (size_t)bh * 65536;
  const u16* Kh = Kb + (size_t)bh * 65536;
  const u16* Vh = V + (size_t)bh * 65536;

  __shared__ u16 Vt[64][40];   // [d][key32], padded
  __shared__ u16 Pl[16][40];   // [q][key32], padded

  const bf16x8 aq0 = *(const bf16x8*)(Qh + (q0 + c) * 64 + g * 8);
  const bf16x8 aq1 = *(const bf16x8*)(Qh + (q0 + c) * 64 + 32 + g * 8);

  f32x4 Oacc[4] = {};
  float Mr[4] = {-1e30f, -1e30f, -1e30f, -1e30f};
  float Lr[4] = {};

  const int nIt = (qb >> 1) + 1;
  for (int it = 0; it < nIt; ++it) {
    const int k0 = it << 5;
    f32x4 S0 = {}, S1 = {};
    {
      bf16x8 b0 = *(const bf16x8*)(Kh + (k0 + c) * 64 + g * 8);
      bf16x8 b1 = *(const bf16x8*)(Kh + (k0 + c) * 64 + 32 + g * 8);
      S0 = __builtin_amdgcn_mfma_f32_16x16x32_bf16(aq0, b0, S0, 0, 0, 0);
      S0 = __builtin_amdgcn_mfma_f32_16x16x32_bf16(aq1, b1, S0, 0, 0, 0);
      bf16x8 b2 = *(const bf16x8*)(Kh + (k0 + 16 + c) * 64 + g * 8);
      bf16x8 b3 = *(const bf16x8*)(Kh + (k0 + 16 + c) * 64 + 32 + g * 8);
      S1 = __builtin_amdgcn_mfma_f32_16x16x32_bf16(aq0, b2, S1, 0, 0, 0);
      S1 = __builtin_amdgcn_mfma_f32_16x16x32_bf16(aq1, b3, S1, 0, 0, 0);
    }
    // stage V transposed: Vt[d][key]
#pragma unroll
    for (int p = 0; p < 4; ++p) {
      int key = (p << 3) + (lane >> 3);
      int d0 = (lane & 7) << 3;
      u16x8 vv = *(const u16x8*)(Vh + (size_t)(k0 + key) * 64 + d0);
#pragma unroll
      for (int j = 0; j < 8; ++j) Vt[d0 + j][key] = vv[j];
    }
    // online softmax over the 32-key window
    const float scale = 0.125f;
#pragma unroll
    for (int r = 0; r < 4; ++r) {
      int q = q0 + (g << 2) + r;
      float s0 = (k0 + c <= q) ? S0[r] * scale : -1e30f;
      float s1 = (k0 + 16 + c <= q) ? S1[r] * scale : -1e30f;
      float m = fmaxf(s0, s1);
      m = fmaxf(m, __shfl_xor(m, 1));
      m = fmaxf(m, __shfl_xor(m, 2));
      m = fmaxf(m, __shfl_xor(m, 4));
      m = fmaxf(m, __shfl_xor(m, 8));
      float mnew = fmaxf(Mr[r], m);
      float p0 = expf(s0 - mnew);
      float p1 = expf(s1 - mnew);
      float rs = p0 + p1;
      rs += __shfl_xor(rs, 1);
      rs += __shfl_xor(rs, 2);
      rs += __shfl_xor(rs, 4);
      rs += __shfl_xor(rs, 8);
      float alpha = expf(Mr[r] - mnew);
      Lr[r] = Lr[r] * alpha + rs;
      Mr[r] = mnew;
#pragma unroll
      for (int nb = 0; nb < 4; ++nb) Oacc[nb][r] *= alpha;
      Pl[(g << 2) + r][c] = f2bf(p0);
      Pl[(g << 2) + r][16 + c] = f2bf(p1);
    }
    // PV (single wave: DS ops are in-order, no barrier needed)
    bf16x8 ap = *(const bf16x8*)&Pl[c][g * 8];
#pragma unroll
    for (int nb = 0; nb < 4; ++nb) {
      bf16x8 bv = *(const bf16x8*)&Vt[nb * 16 + c][g * 8];
      Oacc[nb] = __builtin_amdgcn_mfma_f32_16x16x32_bf16(ap, bv, Oacc[nb], 0, 0, 0);
    }
  }
  const int b = bh >> 4, hh = bh & 15;
#pragma unroll
  for (int r = 0; r < 4; ++r) {
    int tt = q0 + (g << 2) + r;
    float invl = 1.0f / Lr[r];
#pragma unroll
    for (int nb = 0; nb < 4; ++nb) {
      int d = nb * 16 + c;
      O[((size_t)(b * 1024 + tt)) * 1024 + hh * 64 + d] = f2bf(Oacc[nb][r] * invl);
    }
  }
}

// ---------------- launch ----------------
extern "C" void kernel_launch(void* const* d_in, const int* in_sizes, int n_in,
                              void* d_out, int out_size, void* d_ws, size_t ws_size,
                              hipStream_t stream) {
  const int*   idx  = (const int*)d_in[0];
  const float* tok  = (const float*)d_in[1];
  const float* pos  = (const float*)d_in[2];
  const float* Wq   = (const float*)d_in[3];
  const float* Wk   = (const float*)d_in[4];
  const float* Wv   = (const float*)d_in[5];
  const float* Wo   = (const float*)d_in[6];
  const float* bo   = (const float*)d_in[7];
  const float* ln1s = (const float*)d_in[8];
  const float* ln1b = (const float*)d_in[9];
  const float* ln2s = (const float*)d_in[10];
  const float* ln2b = (const float*)d_in[11];
  const float* W1   = (const float*)d_in[12];
  const float* b1   = (const float*)d_in[13];
  const float* W2   = (const float*)d_in[14];
  const float* b2   = (const float*)d_in[15];
  const float* lnfs = (const float*)d_in[16];
  const float* lnfb = (const float*)d_in[17];
  const float* Wlm  = (const float*)d_in[18];
  const float* blm  = (const float*)d_in[19];
  float* out = (float*)d_out;

  char* w = (char*)d_ws;
  auto alloc = [&](size_t bytes) {
    char* p = w;
    w += (bytes + 255) & ~(size_t)255;
    return p;
  };
  float* x  = (float*)alloc(2048ull * 1024 * 4);
  u16* h    = (u16*)alloc(2048ull * 1024 * 2);
  u16* qkv  = (u16*)alloc(3ull * 2097152 * 2);
  u16* o    = (u16*)alloc(2048ull * 1024 * 2);
  u16* a1   = (u16*)alloc(2048ull * 4096 * 2);
  u16* arena = (u16*)alloc(32000ull * 1024 * 2);  // reused: per-layer weightsT / WlmT

  dim3 b32(32, 32, 1);

  k_embed<<<2048, 256, 0, stream>>>(idx, tok, pos, x);

  for (int l = 0; l < 4; ++l) {
    u16* qkvT = arena;                       // [3072][1024]
    u16* WoT  = arena + 3ull * 1048576;      // [1024][1024]
    u16* W1T  = arena + 4ull * 1048576;      // [4096][1024]
    u16* W2T  = arena + 8ull * 1048576;      // [1024][4096]
    k_transpose<<<dim3(32, 32), b32, 0, stream>>>(Wq + (size_t)l * 1048576, qkvT,            1024, 1024);
    k_transpose<<<dim3(32, 32), b32, 0, stream>>>(Wk + (size_t)l * 1048576, qkvT + 1048576,  1024, 1024);
    k_transpose<<<dim3(32, 32), b32, 0, stream>>>(Wv + (size_t)l * 1048576, qkvT + 2097152,  1024, 1024);
    k_transpose<<<dim3(32, 32), b32, 0, stream>>>(Wo + (size_t)l * 1048576, WoT, 1024, 1024);
    k_transpose<<<dim3(128, 32), b32, 0, stream>>>(W1 + (size_t)l * 4194304, W1T, 1024, 4096);
    k_transpose<<<dim3(32, 128), b32, 0, stream>>>(W2 + (size_t)l * 4194304, W2T, 4096, 1024);

    k_ln<<<2048, 256, 0, stream>>>(x, ln1s + l * 1024, ln1b + l * 1024, h);
    k_gemm<EPI_QKV><<<dim3(16, 24), 256, 0, stream>>>(h, qkvT, nullptr, nullptr, qkv,
                                                      2048, 3072, 1024);
    k_attn<<<dim3(64, 32), 64, 0, stream>>>(qkv, qkv + 2097152, qkv + 2 * 2097152, o);
    k_gemm<EPI_RES><<<dim3(16, 8), 256, 0, stream>>>(o, WoT, bo + l * 1024, x, nullptr,
                                                     2048, 1024, 1024);
    k_ln<<<2048, 256, 0, stream>>>(x, ln2s + l * 1024, ln2b + l * 1024, h);
    k_gemm<EPI_RELU><<<dim3(16, 32), 256, 0, stream>>>(h, W1T, b1 + l * 4096, nullptr, a1,
                                                       2048, 4096, 1024);
    k_gemm<EPI_RES><<<dim3(16, 8), 256, 0, stream>>>(a1, W2T, b2 + l * 1024, x, nullptr,
                                                     2048, 1024, 4096);
  }

  k_ln<<<2048, 256, 0, stream>>>(x, lnfs, lnfb, h);
  // LM head: transpose Wlm into arena (layer weights no longer needed)
  k_transpose<<<dim3(1000, 32), b32, 0, stream>>>(Wlm, arena, 1024, 32000);
  k_gemm<EPI_OUT><<<dim3(16, 250), 256, 0, stream>>>(h, arena, blm, out, nullptr,
                                                     2048, 32000, 1024);
}

// Round 2
// 1497.924 us; speedup vs baseline: 1.9886x; 1.9886x over previous
//
#include <hip/hip_runtime.h>

typedef unsigned short u16;
typedef unsigned int u32;
typedef __bf16 bf16x8 __attribute__((ext_vector_type(8)));
typedef float f32x4 __attribute__((ext_vector_type(4)));
typedef u16 u16x8 __attribute__((ext_vector_type(8)));
typedef u16 u16x4 __attribute__((ext_vector_type(4)));

static __device__ __forceinline__ u16 f2bf(float f) {
  u32 u = __builtin_bit_cast(u32, f);
  u32 r = (u + 0x7FFFu + ((u >> 16) & 1u)) >> 16;  // RNE; inputs finite
  return (u16)r;
}

#define GLOAD_LDS16(gp, lp)                                                   \
  __builtin_amdgcn_global_load_lds(                                           \
      (const __attribute__((address_space(1))) void*)(gp),                    \
      (__attribute__((address_space(3))) void*)(lp), 16, 0, 0)

// ---------------- embedding: x = tok_emb[idx] + pos_emb ----------------
__global__ void k_embed(const int* __restrict__ idx, const float* __restrict__ tok,
                        const float* __restrict__ pos, float* __restrict__ x) {
  int row = blockIdx.x;            // b*1024 + t
  int t = row & 1023;
  int id = idx[row];
  int c = threadIdx.x * 4;
  float4 a = *(const float4*)(tok + (size_t)id * 1024 + c);
  float4 p = *(const float4*)(pos + (size_t)t * 1024 + c);
  float4 r{a.x + p.x, a.y + p.y, a.z + p.z, a.w + p.w};
  *(float4*)(x + (size_t)row * 1024 + c) = r;
}

// ---------------- layernorm (f32 in) -> bf16 out ----------------
__global__ void k_ln(const float* __restrict__ x, const float* __restrict__ sc,
                     const float* __restrict__ bi, u16* __restrict__ out) {
  int row = blockIdx.x;
  int t = threadIdx.x;
  const float* xr = x + (size_t)row * 1024;
  float4 v = *(const float4*)(xr + t * 4);
  float s = v.x + v.y + v.z + v.w;
  float ss = v.x * v.x + v.y * v.y + v.z * v.z + v.w * v.w;
  for (int d = 1; d < 64; d <<= 1) { s += __shfl_xor(s, d); ss += __shfl_xor(ss, d); }
  __shared__ float red[8];
  int wave = t >> 6, lane = t & 63;
  if (lane == 0) { red[wave] = s; red[wave + 4] = ss; }
  __syncthreads();
  s = red[0] + red[1] + red[2] + red[3];
  ss = red[4] + red[5] + red[6] + red[7];
  float mu = s * (1.0f / 1024.0f);
  float var = ss * (1.0f / 1024.0f) - mu * mu;
  float inv = rsqrtf(var + 1e-5f);
  float4 g = *(const float4*)(sc + t * 4);
  float4 b = *(const float4*)(bi + t * 4);
  u16x4 o;
  o[0] = f2bf((v.x - mu) * inv * g.x + b.x);
  o[1] = f2bf((v.y - mu) * inv * g.y + b.y);
  o[2] = f2bf((v.z - mu) * inv * g.z + b.z);
  o[3] = f2bf((v.w - mu) * inv * g.w + b.w);
  *(u16x4*)(out + (size_t)row * 1024 + t * 4) = o;
}

// ---------------- transpose+convert: f32 src[R][C] -> bf16 dst[C][R] ----------------
__launch_bounds__(1024)
__global__ void k_transpose(const float* __restrict__ src, u16* __restrict__ dst,
                            int R, int C) {
  __shared__ float tile[32][33];
  int tx = threadIdx.x, ty = threadIdx.y;
  int c = blockIdx.x * 32 + tx;
  int r = blockIdx.y * 32 + ty;
  tile[ty][tx] = src[(size_t)r * C + c];
  __syncthreads();
  int dr = blockIdx.x * 32 + ty;   // dst row = src col
  int dc = blockIdx.y * 32 + tx;   // dst col = src row
  dst[(size_t)dr * R + dc] = f2bf(tile[tx][ty]);
}

// ---------------- GEMM: C[M][N] = A[M][K](bf16) x Bt[N][K](bf16)^T ----------------
// 2-phase pipelined: global_load_lds staging, double-buffered LDS, 1 barrier/K-step.
enum { EPI_QKV = 0, EPI_RES = 1, EPI_RELU = 2, EPI_OUT = 3 };

template <int EPI>
__launch_bounds__(256, 3)
__global__ void k_gemm(const u16* __restrict__ A, const u16* __restrict__ Bt,
                       const float* __restrict__ bias, float* __restrict__ fout,
                       u16* __restrict__ bout, int M, int N, int K) {
  // [buf][A=0/B=1][row 0..127][k 0..31] bf16; 32 KiB total
  __shared__ alignas(16) u16 sm[2][2][128][32];
  const int t = threadIdx.x;
  const int wave = t >> 6, lane = t & 63;
  const int wm = wave >> 1, wn = wave & 1;
  const int g = lane >> 4, c = lane & 15;
  const int m0 = blockIdx.x * 128, n0 = blockIdx.y * 128;

  // staging: wave `wave` covers rows [wave*32, wave*32+32) in 2 instrs (16 rows each).
  // lane l -> row +(l>>2), k-seg (l&3)*8; LDS linear: base + l*16 bytes.
  const int srow = wave * 32 + (lane >> 2);
  const int sseg = (lane & 3) * 8;
  const u16* gA = A + (size_t)(m0 + srow) * K + sseg;
  const u16* gB = Bt + (size_t)(n0 + srow) * K + sseg;

  f32x4 acc[4][4] = {};

  const int nK = K >> 5;
  int cur = 0;

  // prologue: stage tile 0
#pragma unroll
  for (int p = 0; p < 2; ++p) {
    GLOAD_LDS16(gA + (size_t)p * 16 * K, &sm[0][0][wave * 32 + p * 16][0]);
    GLOAD_LDS16(gB + (size_t)p * 16 * K, &sm[0][1][wave * 32 + p * 16][0]);
  }
  __syncthreads();  // compiler drains vmcnt before barrier -> tile 0 resident

  for (int kt = 0; kt < nK; ++kt) {
    // issue next-tile staging first (overlaps with ds_read+MFMA below)
    if (kt + 1 < nK) {
      const int k0 = (kt + 1) << 5;
#pragma unroll
      for (int p = 0; p < 2; ++p) {
        GLOAD_LDS16(gA + k0 + (size_t)p * 16 * K, &sm[cur ^ 1][0][wave * 32 + p * 16][0]);
        GLOAD_LDS16(gB + k0 + (size_t)p * 16 * K, &sm[cur ^ 1][1][wave * 32 + p * 16][0]);
      }
    }
    bf16x8 af[4], bfr[4];
#pragma unroll
    for (int i = 0; i < 4; ++i) {
      af[i]  = *(const bf16x8*)&sm[cur][0][wm * 64 + i * 16 + c][g * 8];
      bfr[i] = *(const bf16x8*)&sm[cur][1][wn * 64 + i * 16 + c][g * 8];
    }
#pragma unroll
    for (int i = 0; i < 4; ++i)
#pragma unroll
      for (int j = 0; j < 4; ++j)
        acc[i][j] = __builtin_amdgcn_mfma_f32_16x16x32_bf16(af[i], bfr[j], acc[i][j], 0, 0, 0);
    __syncthreads();  // drains vmcnt -> next tile resident; all reads of cur done
    cur ^= 1;
  }

  if (EPI == EPI_OUT) {
    // LDS-staged coalesced f32 stores: full 512B rows
    float (*st)[132] = (float(*)[132])sm;
#pragma unroll
    for (int i = 0; i < 4; ++i) {
#pragma unroll
      for (int j = 0; j < 4; ++j)
#pragma unroll
        for (int r = 0; r < 4; ++r)
          st[wm * 16 + g * 4 + r][wn * 64 + j * 16 + c] = acc[i][j][r];
      __syncthreads();
      {
        int row = t >> 3;            // 0..31
        int cs = (t & 7) * 16;       // 0..112
        int m = m0 + (row >> 4) * 64 + i * 16 + (row & 15);
        float* dst = fout + (size_t)m * N + n0 + cs;
#pragma unroll
        for (int q = 0; q < 4; ++q) {
          float4 v = *(const float4*)&st[row][cs + q * 4];
          float4 bb = *(const float4*)&bias[n0 + cs + q * 4];
          float4 o{v.x + bb.x, v.y + bb.y, v.z + bb.z, v.w + bb.w};
          *(float4*)(dst + q * 4) = o;
        }
      }
      __syncthreads();
    }
    return;
  }

#pragma unroll
  for (int i = 0; i < 4; ++i) {
#pragma unroll
    for (int j = 0; j < 4; ++j) {
#pragma unroll
      for (int r = 0; r < 4; ++r) {
        int m = m0 + wm * 64 + i * 16 + g * 4 + r;
        int n = n0 + wn * 64 + j * 16 + c;
        float v = acc[i][j][r];
        if (EPI == EPI_QKV) {
          int which = n >> 10;
          int hh = (n >> 6) & 15, f = n & 63;
          int b = m >> 10, tt = m & 1023;
          bout[(size_t)which * 2097152 +
               ((size_t)(b * 16 + hh) * 1024 + tt) * 64 + f] = f2bf(v);
        } else if (EPI == EPI_RES) {
          size_t off = (size_t)m * N + n;
          fout[off] += v + bias[n];
        } else if (EPI == EPI_RELU) {
          float u = v + bias[n];
          bout[(size_t)m * N + n] = f2bf(u > 0.f ? u : 0.f);
        }
      }
    }
  }
}

// ---------------- flash attention: 1 wave per (bh, 16 q-rows) ----------------
__launch_bounds__(64)
__global__ void k_attn(const u16* __restrict__ Q, const u16* __restrict__ Kb,
                       const u16* __restrict__ V, u16* __restrict__ O) {
  const int qb = blockIdx.x;       // 0..63
  const int bh = blockIdx.y;       // 0..31
  const int lane = threadIdx.x;
  const int g = lane >> 4, c = lane & 15;
  const int q0 = qb << 4;
  const u16* Qh = Q + (size_t)bh * 65536;
  const u16* Kh = Kb + (size_t)bh * 65536;
  const u16* Vh = V + (size_t)bh * 65536;

  __shared__ u16 Vt[64][40];   // [d][key32], padded
  __shared__ u16 Pl[16][40];   // [q][key32], padded

  const bf16x8 aq0 = *(const bf16x8*)(Qh + (q0 + c) * 64 + g * 8);
  const bf16x8 aq1 = *(const bf16x8*)(Qh + (q0 + c) * 64 + 32 + g * 8);

  f32x4 Oacc[4] = {};
  float Mr[4] = {-1e30f, -1e30f, -1e30f, -1e30f};
  float Lr[4] = {};

  const int nIt = (qb >> 1) + 1;
  for (int it = 0; it < nIt; ++it) {
    const int k0 = it << 5;
    f32x4 S0 = {}, S1 = {};
    {
      bf16x8 b0 = *(const bf16x8*)(Kh + (k0 + c) * 64 + g * 8);
      bf16x8 b1 = *(const bf16x8*)(Kh + (k0 + c) * 64 + 32 + g * 8);
      S0 = __builtin_amdgcn_mfma_f32_16x16x32_bf16(aq0, b0, S0, 0, 0, 0);
      S0 = __builtin_amdgcn_mfma_f32_16x16x32_bf16(aq1, b1, S0, 0, 0, 0);
      bf16x8 b2 = *(const bf16x8*)(Kh + (k0 + 16 + c) * 64 + g * 8);
      bf16x8 b3 = *(const bf16x8*)(Kh + (k0 + 16 + c) * 64 + 32 + g * 8);
      S1 = __builtin_amdgcn_mfma_f32_16x16x32_bf16(aq0, b2, S1, 0, 0, 0);
      S1 = __builtin_amdgcn_mfma_f32_16x16x32_bf16(aq1, b3, S1, 0, 0, 0);
    }
    // stage V transposed: Vt[d][key]
#pragma unroll
    for (int p = 0; p < 4; ++p) {
      int key = (p << 3) + (lane >> 3);
      int d0 = (lane & 7) << 3;
      u16x8 vv = *(const u16x8*)(Vh + (size_t)(k0 + key) * 64 + d0);
#pragma unroll
      for (int j = 0; j < 8; ++j) Vt[d0 + j][key] = vv[j];
    }
    // online softmax over the 32-key window
    const float scale = 0.125f;
#pragma unroll
    for (int r = 0; r < 4; ++r) {
      int q = q0 + (g << 2) + r;
      float s0 = (k0 + c <= q) ? S0[r] * scale : -1e30f;
      float s1 = (k0 + 16 + c <= q) ? S1[r] * scale : -1e30f;
      float m = fmaxf(s0, s1);
      m = fmaxf(m, __shfl_xor(m, 1));
      m = fmaxf(m, __shfl_xor(m, 2));
      m = fmaxf(m, __shfl_xor(m, 4));
      m = fmaxf(m, __shfl_xor(m, 8));
      float mnew = fmaxf(Mr[r], m);
      float p0 = expf(s0 - mnew);
      float p1 = expf(s1 - mnew);
      float rs = p0 + p1;
      rs += __shfl_xor(rs, 1);
      rs += __shfl_xor(rs, 2);
      rs += __shfl_xor(rs, 4);
      rs += __shfl_xor(rs, 8);
      float alpha = expf(Mr[r] - mnew);
      Lr[r] = Lr[r] * alpha + rs;
      Mr[r] = mnew;
#pragma unroll
      for (int nb = 0; nb < 4; ++nb) Oacc[nb][r] *= alpha;
      Pl[(g << 2) + r][c] = f2bf(p0);
      Pl[(g << 2) + r][16 + c] = f2bf(p1);
    }
    // PV (single wave: DS ops are in-order, no barrier needed)
    bf16x8 ap = *(const bf16x8*)&Pl[c][g * 8];
#pragma unroll
    for (int nb = 0; nb < 4; ++nb) {
      bf16x8 bv = *(const bf16x8*)&Vt[nb * 16 + c][g * 8];
      Oacc[nb] = __builtin_amdgcn_mfma_f32_16x16x32_bf16(ap, bv, Oacc[nb], 0, 0, 0);
    }
  }
  const int b = bh >> 4, hh = bh & 15;
#pragma unroll
  for (int r = 0; r < 4; ++r) {
    int tt = q0 + (g << 2) + r;
    float invl = 1.0f / Lr[r];
#pragma unroll
    for (int nb = 0; nb < 4; ++nb) {
      int d = nb * 16 + c;
      O[((size_t)(b * 1024 + tt)) * 1024 + hh * 64 + d] = f2bf(Oacc[nb][r] * invl);
    }
  }
}

// ---------------- launch ----------------
extern "C" void kernel_launch(void* const* d_in, const int* in_sizes, int n_in,
                              void* d_out, int out_size, void* d_ws, size_t ws_size,
                              hipStream_t stream) {
  const int*   idx  = (const int*)d_in[0];
  const float* tok  = (const float*)d_in[1];
  const float* pos  = (const float*)d_in[2];
  const float* Wq   = (const float*)d_in[3];
  const float* Wk   = (const float*)d_in[4];
  const float* Wv   = (const float*)d_in[5];
  const float* Wo   = (const float*)d_in[6];
  const float* bo   = (const float*)d_in[7];
  const float* ln1s = (const float*)d_in[8];
  const float* ln1b = (const float*)d_in[9];
  const float* ln2s = (const float*)d_in[10];
  const float* ln2b = (const float*)d_in[11];
  const float* W1   = (const float*)d_in[12];
  const float* b1   = (const float*)d_in[13];
  const float* W2   = (const float*)d_in[14];
  const float* b2   = (const float*)d_in[15];
  const float* lnfs = (const float*)d_in[16];
  const float* lnfb = (const float*)d_in[17];
  const float* Wlm  = (const float*)d_in[18];
  const float* blm  = (const float*)d_in[19];
  float* out = (float*)d_out;

  char* w = (char*)d_ws;
  auto alloc = [&](size_t bytes) {
    char* p = w;
    w += (bytes + 255) & ~(size_t)255;
    return p;
  };
  float* x  = (float*)alloc(2048ull * 1024 * 4);
  u16* h    = (u16*)alloc(2048ull * 1024 * 2);
  u16* qkv  = (u16*)alloc(3ull * 2097152 * 2);
  u16* o    = (u16*)alloc(2048ull * 1024 * 2);
  u16* a1   = (u16*)alloc(2048ull * 4096 * 2);
  u16* arena = (u16*)alloc(32000ull * 1024 * 2);  // reused: per-layer weightsT / WlmT

  dim3 b32(32, 32, 1);

  k_embed<<<2048, 256, 0, stream>>>(idx, tok, pos, x);

  for (int l = 0; l < 4; ++l) {
    u16* qkvT = arena;                       // [3072][1024]
    u16* WoT  = arena + 3ull * 1048576;      // [1024][1024]
    u16* W1T  = arena + 4ull * 1048576;      // [4096][1024]
    u16* W2T  = arena + 8ull * 1048576;      // [1024][4096]
    k_transpose<<<dim3(32, 32), b32, 0, stream>>>(Wq + (size_t)l * 1048576, qkvT,            1024, 1024);
    k_transpose<<<dim3(32, 32), b32, 0, stream>>>(Wk + (size_t)l * 1048576, qkvT + 1048576,  1024, 1024);
    k_transpose<<<dim3(32, 32), b32, 0, stream>>>(Wv + (size_t)l * 1048576, qkvT + 2097152,  1024, 1024);
    k_transpose<<<dim3(32, 32), b32, 0, stream>>>(Wo + (size_t)l * 1048576, WoT, 1024, 1024);
    k_transpose<<<dim3(128, 32), b32, 0, stream>>>(W1 + (size_t)l * 4194304, W1T, 1024, 4096);
    k_transpose<<<dim3(32, 128), b32, 0, stream>>>(W2 + (size_t)l * 4194304, W2T, 4096, 1024);

    k_ln<<<2048, 256, 0, stream>>>(x, ln1s + l * 1024, ln1b + l * 1024, h);
    k_gemm<EPI_QKV><<<dim3(16, 24), 256, 0, stream>>>(h, qkvT, nullptr, nullptr, qkv,
                                                      2048, 3072, 1024);
    k_attn<<<dim3(64, 32), 64, 0, stream>>>(qkv, qkv + 2097152, qkv + 2 * 2097152, o);
    k_gemm<EPI_RES><<<dim3(16, 8), 256, 0, stream>>>(o, WoT, bo + l * 1024, x, nullptr,
                                                     2048, 1024, 1024);
    k_ln<<<2048, 256, 0, stream>>>(x, ln2s + l * 1024, ln2b + l * 1024, h);
    k_gemm<EPI_RELU><<<dim3(16, 32), 256, 0, stream>>>(h, W1T, b1 + l * 4096, nullptr, a1,
                                                       2048, 4096, 1024);
    k_gemm<EPI_RES><<<dim3(16, 8), 256, 0, stream>>>(a1, W2T, b2 + l * 1024, x, nullptr,
                                                     2048, 1024, 4096);
  }

  k_ln<<<2048, 256, 0, stream>>>(x, lnfs, lnfb, h);
  // LM head: transpose Wlm into arena (layer weights no longer needed)
  k_transpose<<<dim3(1000, 32), b32, 0, stream>>>(Wlm, arena, 1024, 32000);
  k_gemm<EPI_OUT><<<dim3(16, 250), 256, 0, stream>>>(h, arena, blm, out, nullptr,
                                                     2048, 32000, 1024);
}